// Round 2
// baseline (713.637 us; speedup 1.0000x reference)
//
#include <hip/hip_runtime.h>

#define B_ 16
#define C_ 128
#define L_ 2048

typedef unsigned short u16;
typedef __bf16 bf16x8 __attribute__((ext_vector_type(8)));
typedef float floatx4 __attribute__((ext_vector_type(4)));

static __device__ __forceinline__ u16 f_to_bf16(float f) {
    union { float f; unsigned int i; } v;
    v.f = f;
    unsigned int x = v.i;
    return (u16)((x + 0x7fffu + ((x >> 16) & 1u)) >> 16);
}
static __device__ __forceinline__ bf16x8 lds_load8(const u16* p) {
    union { uint2 a[2]; bf16x8 v; } u;
    u.a[0] = *(const uint2*)p;
    u.a[1] = *(const uint2*)(p + 4);
    return u.v;
}

// ---------------- K0: KT[b][k][c] = bf16(K[b][c][k]) ----------------
__global__ void k_transpose(const float* __restrict__ K, u16* __restrict__ KT) {
    int t  = blockIdx.x * blockDim.x + threadIdx.x;   // B*L*4 threads
    int k  = t & (L_ - 1);
    int ch = (t >> 11) & 3;          // 4 chunks of 32 c each
    int b  = t >> 13;
    const float* src = K + (size_t)b * C_ * L_ + (size_t)(ch * 32) * L_ + k;
    u16* dst = KT + ((size_t)b * L_ + k) * C_ + ch * 32;
    u16 v[32];
#pragma unroll
    for (int c = 0; c < 32; ++c) v[c] = f_to_bf16(src[(size_t)c * L_]);
#pragma unroll
    for (int c = 0; c < 32; c += 8) {
        union { u16 u[8]; uint4 q; } p;
#pragma unroll
        for (int j = 0; j < 8; ++j) p.u[j] = v[c + j];
        *(uint4*)(dst + c) = p.q;
    }
}

// ---------------- K1: S = Q^T K (scaled + logmask), softmax, write P^T ----
// Register-resident S strip: each wave holds S[16 q][256 k] in 16 MFMA acc tiles.
#define BM 16
#define QS 136    // Qs row stride (u16): 272B rows, 16B aligned

__launch_bounds__(512)
__global__ void k_attn(const float* __restrict__ Q, const u16* __restrict__ KT,
                       const float* __restrict__ M, float* __restrict__ PT) {
    __shared__ u16   Qs[BM * QS];      // 4352 B
    __shared__ float redmax[BM * 8];   // [row][wave]
    __shared__ float redsum[BM * 8];

    const int b    = blockIdx.y;
    const int q0   = blockIdx.x * BM;
    const int tid  = threadIdx.x;
    const int lane = tid & 63;
    const int wave = tid >> 6;         // 0..7, covers keys [wave*256, wave*256+256)
    const int m16  = lane & 15;
    const int quad = lane >> 4;

    // stage Q strip transposed+cast: Qs[q][c] = bf16(Q[b][c][q0+q])
    for (int i = tid; i < BM * C_; i += 512) {
        int q = i & 15, c = i >> 4;
        Qs[q * QS + c] = f_to_bf16(Q[((size_t)b * C_ + c) * L_ + q0 + q]);
    }
    __syncthreads();

    // A-fragments (loop-invariant): A[m=lane&15][kk=f*32+quad*8+j]
    bf16x8 afr[4];
#pragma unroll
    for (int f = 0; f < 4; ++f)
        afr[f] = *(const bf16x8*)(Qs + m16 * QS + f * 32 + quad * 8);

    const u16*  ktb = KT + (size_t)b * L_ * C_;
    const float* mb = M + (size_t)b * L_;
    const float scale = 0.08838834764831845f;   // 1/sqrt(128)

    // Phase A: 16 tiles of S = scale*QK + log(mask+1e-6), kept in registers.
    floatx4 accf[16];
#pragma unroll
    for (int t = 0; t < 16; ++t) {
        const int k0 = (wave << 8) + (t << 4);
        const u16* kr = ktb + (size_t)(k0 + m16) * C_ + quad * 8;
        floatx4 acc = {0.f, 0.f, 0.f, 0.f};
#pragma unroll
        for (int f = 0; f < 4; ++f) {
            bf16x8 bfr = *(const bf16x8*)(kr + f * 32);  // B[kk][n=key]
            acc = __builtin_amdgcn_mfma_f32_16x16x32_bf16(afr[f], bfr, acc, 0, 0, 0);
        }
        const float lm = __logf(mb[k0 + m16] + 1e-6f);
#pragma unroll
        for (int r = 0; r < 4; ++r) acc[r] = acc[r] * scale + lm;
        accf[t] = acc;
    }

    // Phase B: row max. Lane (quad,m16) holds rows quad*4+r, cols k0+m16.
    float gm[4];
#pragma unroll
    for (int r = 0; r < 4; ++r) {
        float v = accf[0][r];
#pragma unroll
        for (int t = 1; t < 16; ++t) v = fmaxf(v, accf[t][r]);
        v = fmaxf(v, __shfl_xor(v, 1, 64));
        v = fmaxf(v, __shfl_xor(v, 2, 64));
        v = fmaxf(v, __shfl_xor(v, 4, 64));
        v = fmaxf(v, __shfl_xor(v, 8, 64));
        if (m16 == 0) redmax[(quad * 4 + r) * 8 + wave] = v;
    }
    __syncthreads();
#pragma unroll
    for (int r = 0; r < 4; ++r) {
        float v = redmax[(quad * 4 + r) * 8];
#pragma unroll
        for (int w = 1; w < 8; ++w) v = fmaxf(v, redmax[(quad * 4 + r) * 8 + w]);
        gm[r] = v;
    }

    // Phase C: exp in place + row sum.
    float rs[4] = {0.f, 0.f, 0.f, 0.f};
#pragma unroll
    for (int t = 0; t < 16; ++t)
#pragma unroll
        for (int r = 0; r < 4; ++r) {
            float e = __expf(accf[t][r] - gm[r]);
            accf[t][r] = e;
            rs[r] += e;
        }
#pragma unroll
    for (int r = 0; r < 4; ++r) {
        float v = rs[r];
        v += __shfl_xor(v, 1, 64);
        v += __shfl_xor(v, 2, 64);
        v += __shfl_xor(v, 4, 64);
        v += __shfl_xor(v, 8, 64);
        if (m16 == 0) redsum[(quad * 4 + r) * 8 + wave] = v;
    }
    __syncthreads();
    float rinv[4];
#pragma unroll
    for (int r = 0; r < 4; ++r) {
        float v = redsum[(quad * 4 + r) * 8];
#pragma unroll
        for (int w = 1; w < 8; ++w) v += redsum[(quad * 4 + r) * 8 + w];
        rinv[r] = 1.f / v;
    }

    // Phase D: P^T[b][k][q0+quad*4 .. +4] as float4 per lane per tile.
    float* pt = PT + (size_t)b * L_ * L_ + q0 + quad * 4;
#pragma unroll
    for (int t = 0; t < 16; ++t) {
        const int k = (wave << 8) + (t << 4) + m16;
        const float mk = mb[k];                       // multiplicative mask
        floatx4 o;
#pragma unroll
        for (int r = 0; r < 4; ++r) o[r] = accf[t][r] * rinv[r] * mk;
        *(floatx4*)(pt + (size_t)k * L_) = o;
    }
}

// ---------------- K3: out[b][c][q] = sum_k V[b][c][k] * P^T[b][k][q] -------
#define TN 128
#define TK 32
#define VS 36    // LDS row stride (u16): 72B rows -> ~2-way bank pattern

__launch_bounds__(256, 2)
__global__ void k_out(const float* __restrict__ V, const float* __restrict__ PT,
                      float* __restrict__ OUT) {
    __shared__ u16 Vs[C_ * VS];   // [c][k] (k contiguous), bf16
    __shared__ u16 Bs[TN * VS];   // [q][k] (k contiguous), bf16

    const int b    = blockIdx.y;
    const int n0   = blockIdx.x * TN;
    const int tid  = threadIdx.x;
    const int lane = tid & 63;
    const int wave = tid >> 6;    // 0..3
    const int m16  = lane & 15;
    const int quad = lane >> 4;
    const int wc   = wave >> 1;   // c half
    const int wn   = wave & 1;    // q half

    floatx4 acc[4][4];
#pragma unroll
    for (int i = 0; i < 4; ++i)
#pragma unroll
        for (int j = 0; j < 4; ++j) acc[i][j] = (floatx4){0.f, 0.f, 0.f, 0.f};

    const float* vb = V + (size_t)b * C_ * L_;
    const float* pb = PT + (size_t)b * L_ * L_ + n0;

    for (int k0 = 0; k0 < L_; k0 += TK) {
        __syncthreads();
#pragma unroll
        for (int ii = 0; ii < 2; ++ii) {
            int s = tid + ii * 256;
            // V slab [128 c][32 k]: 8 floats per thread, cast to bf16
            int c = s >> 2, part = s & 3;
            const floatx4 a0 = *(const floatx4*)(vb + (size_t)c * L_ + k0 + part * 8);
            const floatx4 a1 = *(const floatx4*)(vb + (size_t)c * L_ + k0 + part * 8 + 4);
            union { u16 u[8]; uint2 d[2]; } pk;
#pragma unroll
            for (int j = 0; j < 4; ++j) { pk.u[j] = f_to_bf16(a0[j]); pk.u[4 + j] = f_to_bf16(a1[j]); }
            *(uint2*)(Vs + c * VS + part * 8)     = pk.d[0];
            *(uint2*)(Vs + c * VS + part * 8 + 4) = pk.d[1];
            // Bs [128 q][32 k] transposed from P^T rows
            int kk = s >> 4, qo = (s & 15) * 8;
            const floatx4 p0 = *(const floatx4*)(pb + (size_t)(k0 + kk) * L_ + qo);
            const floatx4 p1 = *(const floatx4*)(pb + (size_t)(k0 + kk) * L_ + qo + 4);
#pragma unroll
            for (int j = 0; j < 4; ++j) {
                Bs[(qo + j) * VS + kk]     = f_to_bf16(p0[j]);
                Bs[(qo + 4 + j) * VS + kk] = f_to_bf16(p1[j]);
            }
        }
        __syncthreads();

        bf16x8 af[4], bfr[4];
#pragma unroll
        for (int i = 0; i < 4; ++i)
            af[i] = lds_load8(Vs + (wc * 64 + i * 16 + m16) * VS + quad * 8);
#pragma unroll
        for (int j = 0; j < 4; ++j)
            bfr[j] = lds_load8(Bs + (wn * 64 + j * 16 + m16) * VS + quad * 8);
#pragma unroll
        for (int i = 0; i < 4; ++i)
#pragma unroll
            for (int j = 0; j < 4; ++j)
                acc[i][j] = __builtin_amdgcn_mfma_f32_16x16x32_bf16(af[i], bfr[j], acc[i][j], 0, 0, 0);
    }

    float* ob = OUT + (size_t)b * C_ * L_;
#pragma unroll
    for (int i = 0; i < 4; ++i) {
        const int c = wc * 64 + i * 16 + quad * 4;    // row = quad*4+r
#pragma unroll
        for (int j = 0; j < 4; ++j) {
            const int q = n0 + wn * 64 + j * 16 + m16; // col = m16
#pragma unroll
            for (int r = 0; r < 4; ++r)
                ob[(size_t)(c + r) * L_ + q] = acc[i][j][r];
        }
    }
}

extern "C" void kernel_launch(void* const* d_in, const int* in_sizes, int n_in,
                              void* d_out, int out_size, void* d_ws, size_t ws_size,
                              hipStream_t stream) {
    (void)in_sizes; (void)n_in; (void)out_size; (void)ws_size;
    const float* Q = (const float*)d_in[0];
    const float* K = (const float*)d_in[1];
    const float* V = (const float*)d_in[2];
    const float* M = (const float*)d_in[3];
    float* OUT = (float*)d_out;                     // [B,C,L] fp32
    float* PT  = OUT + (size_t)B_ * C_ * L_;        // [B,Lk,Lq] = attention^T, fp32
    u16*   KT  = (u16*)d_ws;                        // [B,L,C] bf16 scratch (8 MB)

    k_transpose<<<dim3((B_ * L_ * 4) / 256), dim3(256), 0, stream>>>(K, KT);
    k_attn<<<dim3(L_ / BM, B_), dim3(512), 0, stream>>>(Q, KT, M, PT);
    k_out<<<dim3(L_ / TN, B_), dim3(256), 0, stream>>>(V, PT, OUT);
}